// Round 21
// baseline (79.567 us; speedup 1.0000x reference)
//
#include <hip/hip_runtime.h>
#include <hip/hip_bf16.h>

// Problem constants
#define Bn 8
#define Tn 2048
#define En 512
#define Hn 16
#define Dn 32
#define NC 32          // scan chunks
#define CL 64          // chunk length (Tn/NC)
#define NT (Bn*Tn)     // 16384 tokens
#define INV_DECAY (1.0f/1.2f)

typedef __attribute__((ext_vector_type(8))) _Float16 f16x8; // 8 fp16 (4 VGPRs)
typedef __attribute__((ext_vector_type(2))) _Float16 f16x2;
typedef __attribute__((ext_vector_type(4))) float  f32x4;
typedef __attribute__((ext_vector_type(8))) unsigned short u16x8;

__device__ __forceinline__ unsigned short f2h(float f) {
    union { _Float16 h; unsigned short u; } c; c.h = (_Float16)f; return c.u;
}
__device__ __forceinline__ float h2f(unsigned short u) {
    union { _Float16 h; unsigned short u; } c; c.u = u; return (float)c.h;
}

// (1/1.2)^e, compile-time folded under full unroll
__host__ __device__ constexpr float wpow(int e) {
    float r = 1.f;
    for (int i = 0; i < e; i++) r *= (1.0f / 1.2f);
    return r;
}

// Head-major address: hm[hd][tok][ch], ch in [0,32)
__device__ __forceinline__ size_t hm(int hd, int tok, int ch) {
    return (size_t)hd * ((size_t)NT * Dn) + (size_t)tok * Dn + ch;
}

// ---------------- K0: prep --------------------------------------------------
__global__ __launch_bounds__(256) void prep_k(const float* __restrict__ C,
                                              unsigned short* __restrict__ Cl,
                                              const float* __restrict__ W,
                                              unsigned short* __restrict__ Wt) {
    __shared__ float tile[32][33];
    if (blockIdx.x < 256) {
        const int g = blockIdx.x * 256 + threadIdx.x;   // 65536 chunks
        const int hd = g >> 12, rem = g & 4095;
        const int i = rem >> 7, half = (rem >> 6) & 1, lane = rem & 63;
        const int tloc = lane & 15, kgrp = lane >> 4;
        const int k = half * 16 + tloc;
        const float* src = C + (size_t)hd * 32768 + (size_t)k * 1024 + i * 32 + kgrp * 8;
        float4 a = reinterpret_cast<const float4*>(src)[0];
        float4 b = reinterpret_cast<const float4*>(src)[1];
        u16x8 st;
        st[0]=f2h(a.x); st[1]=f2h(a.y); st[2]=f2h(a.z); st[3]=f2h(a.w);
        st[4]=f2h(b.x); st[5]=f2h(b.y); st[6]=f2h(b.z); st[7]=f2h(b.w);
        *reinterpret_cast<u16x8*>(Cl + (size_t)g * 8) = st;
    } else {
        const int bid = blockIdx.x - 256;
        const int kb = (bid & 15) * 32, nb = (bid >> 4) * 32;
        const int tx = threadIdx.x & 31, ty = threadIdx.x >> 5;   // ty 0..7
        #pragma unroll
        for (int j = 0; j < 4; j++)
            tile[ty + 8 * j][tx] = W[(size_t)(kb + ty + 8 * j) * En + nb + tx];
        __syncthreads();
        #pragma unroll
        for (int j = 0; j < 4; j++)
            Wt[(size_t)(nb + ty + 8 * j) * En + kb + tx] = f2h(tile[tx][ty + 8 * j]);
    }
}

// ---------------- K1: h = x @ W + b  (f16 MFMA GEMM, 128x128 tile) ----------
__global__ __launch_bounds__(256) void gemm_mfma_k(const float* __restrict__ x,
                                                   const unsigned short* __restrict__ Wt,
                                                   const float* __restrict__ bias,
                                                   unsigned short* __restrict__ h,
                                                   float* __restrict__ locals) {
    __shared__ unsigned short As[128][40];
    __shared__ unsigned short Bs[128][40];
    const int m0 = blockIdx.x * 128, n0 = blockIdx.y * 128;
    const int tid = threadIdx.x;
    const int wid = tid >> 6, lane = tid & 63;
    const int tloc = lane & 15, kgrp = lane >> 4;
    const int wr = wid >> 1, wc = wid & 1;

    const int sr = tid >> 1, sh = (tid & 1) * 16;

    f32x4 acc[4][4] = {};

    for (int k0 = 0; k0 < En; k0 += 32) {
        const float* xp = &x[(size_t)(m0 + sr) * En + k0 + sh];
        float4 a0 = reinterpret_cast<const float4*>(xp)[0];
        float4 a1 = reinterpret_cast<const float4*>(xp)[1];
        float4 a2 = reinterpret_cast<const float4*>(xp)[2];
        float4 a3 = reinterpret_cast<const float4*>(xp)[3];
        const unsigned short* wp = &Wt[(size_t)(n0 + sr) * En + k0 + sh];
        u16x8 bv0 = reinterpret_cast<const u16x8*>(wp)[0];
        u16x8 bv1 = reinterpret_cast<const u16x8*>(wp)[1];
        __syncthreads();
        u16x8 w0, w1;
        w0[0]=f2h(a0.x); w0[1]=f2h(a0.y); w0[2]=f2h(a0.z); w0[3]=f2h(a0.w);
        w0[4]=f2h(a1.x); w0[5]=f2h(a1.y); w0[6]=f2h(a1.z); w0[7]=f2h(a1.w);
        w1[0]=f2h(a2.x); w1[1]=f2h(a2.y); w1[2]=f2h(a2.z); w1[3]=f2h(a2.w);
        w1[4]=f2h(a3.x); w1[5]=f2h(a3.y); w1[6]=f2h(a3.z); w1[7]=f2h(a3.w);
        *reinterpret_cast<u16x8*>(&As[sr][sh])     = w0;
        *reinterpret_cast<u16x8*>(&As[sr][sh + 8]) = w1;
        *reinterpret_cast<u16x8*>(&Bs[sr][sh])     = bv0;
        *reinterpret_cast<u16x8*>(&Bs[sr][sh + 8]) = bv1;
        __syncthreads();

        f16x8 afr[4], bfr[4];
        #pragma unroll
        for (int m = 0; m < 4; m++)
            afr[m] = *reinterpret_cast<const f16x8*>(&As[wr * 64 + m * 16 + tloc][kgrp * 8]);
        #pragma unroll
        for (int n = 0; n < 4; n++)
            bfr[n] = *reinterpret_cast<const f16x8*>(&Bs[wc * 64 + n * 16 + tloc][kgrp * 8]);
        #pragma unroll
        for (int m = 0; m < 4; m++)
            #pragma unroll
            for (int n = 0; n < 4; n++)
                acc[m][n] = __builtin_amdgcn_mfma_f32_16x16x32_f16(afr[m], bfr[n], acc[m][n], 0, 0, 0);
    }

    const float kmul = (kgrp & 1 ? 2.0736f : 1.f) * (kgrp & 2 ? 4.29981696f : 1.f);
    const int cg = blockIdx.x * 2 + wr;   // global 64-token chunk

    #pragma unroll
    for (int nt = 0; nt < 4; nt++) {
        const int col = n0 + wc * 64 + nt * 16 + tloc;
        const float bcol = bias[col];
        const int hd = col >> 5, ch = col & 31;
        float part = 0.f;
        #pragma unroll
        for (int m = 0; m < 4; m++)
            #pragma unroll
            for (int r = 0; r < 4; r++) {
                const int row = m0 + wr * 64 + m * 16 + kgrp * 4 + r;
                const unsigned short hb16 = f2h(acc[m][nt][r] + bcol);
                h[hm(hd, row, ch)] = hb16;
                part += h2f(hb16) * (wpow(64 - m * 16 - r) * kmul);
            }
        part += __shfl_xor(part, 16);
        part += __shfl_xor(part, 32);
        if (kgrp == 0) locals[(size_t)cg * En + col] = part;
    }
}

// ---------------- K2: fused prefix + emit S (f16, head-major) ---------------
__global__ __launch_bounds__(512) void scan_emit3_k(const unsigned short* __restrict__ h,
                                                    const float* __restrict__ locals,
                                                    unsigned short* __restrict__ Sg) {
    const int c = blockIdx.x, b = blockIdx.y;
    const int e = threadIdx.x;
    const int hd = e >> 5, ch = e & 31;
    constexpr float INVRL = wpow(64);   // d^64

    float A = 0.f, w = 1.f;
    for (int cp = c - 1; cp >= 0; --cp) {
        A += w * locals[(size_t)(b * NC + cp) * En + e];
        w *= INVRL;
    }

    const size_t base = hm(hd, b * Tn + c * CL, ch);
    for (int t = 0; t < CL; t++) {
        Sg[base + (size_t)t * Dn] = f2h(A);
        A = (A + h2f(h[base + (size_t)t * Dn])) * INV_DECAY;
    }
}

// ---------------- K3: bilinear v16 — fp16 lean structure, 2 chunks/block ----
// Block: 256 thr = 4 waves, TWO 64-token chunks x 1 head. afr (C slice)
// loaded once, reused across both chunks (halves the per-block L2 prologue
// and aggregate C traffic). No in-kernel scan, no locals-carry (the r11/r13
// failure mechanisms). ys LDS reused per chunk (1 extra barrier each).
__global__ __launch_bounds__(256, 4) void bilinear16_k(const unsigned short* __restrict__ hg,
                                                       const unsigned short* __restrict__ Sg,
                                                       unsigned short* __restrict__ yb,
                                                       const unsigned short* __restrict__ Cl) {
    __shared__ float ys[4][64][36];   // 36.9 KB

    const int hd = blockIdx.y;
    const int tid = threadIdx.x;
    const int wid = tid >> 6, lane = tid & 63;
    const int tloc = lane & 15, kgrp = lane >> 4;
    const int j0 = kgrp * 8;
    const int tokens00 = blockIdx.x * 128;

    // ---- A-frags: C2 slice (f16), loaded once for both chunks ----
    f16x8 afr[8][2];
    {
        const unsigned short* cb = Cl + (size_t)hd * 32768;
        #pragma unroll
        for (int s = 0; s < 8; s++) {
            const int i = wid * 8 + s;
            #pragma unroll
            for (int mt = 0; mt < 2; mt++)
                afr[s][mt] = *reinterpret_cast<const f16x8*>(
                    cb + ((size_t)((i * 2 + mt) * 64 + lane) * 8));
        }
    }

    for (int cc = 0; cc < 2; cc++) {
        const int tokens0 = tokens00 + cc * 64;

        // ---- h (f16 direct) + S (f16 pairs) fragments per n-tile ----
        f16x8 hreg[4];
        f16x2 sf2[4][4];
        #pragma unroll
        for (int nt = 0; nt < 4; nt++) {
            const int trow = tokens0 + nt * 16 + tloc;
            hreg[nt] = *reinterpret_cast<const f16x8*>(hg + hm(hd, trow, wid * 8));
            f16x8 svh = *reinterpret_cast<const f16x8*>(Sg + hm(hd, trow, j0));
            #pragma unroll
            for (int e2 = 0; e2 < 4; e2++) {
                f16x2 p; p.x = svh[e2 * 2]; p.y = svh[e2 * 2 + 1];
                sf2[nt][e2] = p;
            }
        }

        // ---- main loop: pk_mul product gen + 8 indep f16 MFMA chains ----
        f32x4 acc[2][4] = {};
        #pragma unroll
        for (int s = 0; s < 8; s++) {
            #pragma unroll
            for (int nt = 0; nt < 4; nt++) {
                f16x2 hb; hb.x = hreg[nt][s]; hb.y = hreg[nt][s];
                union { f16x8 v; f16x2 p[4]; } bf;
                bf.p[0] = sf2[nt][0] * hb;
                bf.p[1] = sf2[nt][1] * hb;
                bf.p[2] = sf2[nt][2] * hb;
                bf.p[3] = sf2[nt][3] * hb;
                acc[0][nt] = __builtin_amdgcn_mfma_f32_16x16x32_f16(afr[s][0], bf.v, acc[0][nt], 0, 0, 0);
                acc[1][nt] = __builtin_amdgcn_mfma_f32_16x16x32_f16(afr[s][1], bf.v, acc[1][nt], 0, 0, 0);
            }
        }

        // ---- partials to LDS ----
        #pragma unroll
        for (int mt = 0; mt < 2; mt++)
            #pragma unroll
            for (int nt = 0; nt < 4; nt++)
                *reinterpret_cast<f32x4*>(&ys[wid][nt * 16 + tloc][mt * 16 + kgrp * 4]) = acc[mt][nt];
        __syncthreads();

        // ---- reduce 4 partials + residual (f16), coalesced f16 store ----
        {
            const int token = tid >> 2, q = tid & 3;
            f32x4 y0 = {0.f,0.f,0.f,0.f}, y1 = {0.f,0.f,0.f,0.f};
            #pragma unroll
            for (int w = 0; w < 4; w++) {
                const f32x4* src = reinterpret_cast<const f32x4*>(&ys[w][token][q * 8]);
                y0 += src[0];
                y1 += src[1];
            }
            u16x8 hres = *reinterpret_cast<const u16x8*>(hg + hm(hd, tokens0 + token, q * 8));
            u16x8 st;
            #pragma unroll
            for (int e = 0; e < 4; e++) {
                st[e]     = f2h(y0[e] + h2f(hres[e]));
                st[4 + e] = f2h(y1[e] + h2f(hres[4 + e]));
            }
            *reinterpret_cast<u16x8*>(yb + hm(hd, tokens0 + token, q * 8)) = st;
        }
        if (cc == 0) __syncthreads();   // ys consumed before chunk-1 overwrite
    }
}

// ---------------- K4: LayerNorm over E=512 (head-major f16 in, f32 out) -----
__global__ __launch_bounds__(256) void ln_k(const unsigned short* __restrict__ y,
                                            const float* __restrict__ gamma,
                                            const float* __restrict__ beta,
                                            float* __restrict__ out) {
    const int row = blockIdx.x * 4 + (threadIdx.x >> 6);
    const int lane = threadIdx.x & 63;
    u16x8 v = *reinterpret_cast<const u16x8*>(y + hm(lane >> 2, row, (lane & 3) * 8));
    float f[8];
    float s = 0.f, s2 = 0.f;
    #pragma unroll
    for (int e = 0; e < 8; e++) {
        f[e] = h2f(v[e]);
        s += f[e]; s2 += f[e] * f[e];
    }
    #pragma unroll
    for (int off = 1; off < 64; off <<= 1) {
        s  += __shfl_xor(s, off);
        s2 += __shfl_xor(s2, off);
    }
    const float mu = s * (1.f / En);
    const float var = s2 * (1.f / En) - mu * mu;
    const float rs = rsqrtf(var + 1e-3f);
    const int cbase = lane * 8;
    float4 g0 = reinterpret_cast<const float4*>(&gamma[cbase])[0];
    float4 g1 = reinterpret_cast<const float4*>(&gamma[cbase])[1];
    float4 b0 = reinterpret_cast<const float4*>(&beta[cbase])[0];
    float4 b1 = reinterpret_cast<const float4*>(&beta[cbase])[1];
    float4 o0, o1;
    o0.x = (f[0] - mu) * rs * g0.x + b0.x; o0.y = (f[1] - mu) * rs * g0.y + b0.y;
    o0.z = (f[2] - mu) * rs * g0.z + b0.z; o0.w = (f[3] - mu) * rs * g0.w + b0.w;
    o1.x = (f[4] - mu) * rs * g1.x + b1.x; o1.y = (f[5] - mu) * rs * g1.y + b1.y;
    o1.z = (f[6] - mu) * rs * g1.z + b1.z; o1.w = (f[7] - mu) * rs * g1.w + b1.w;
    float* op = out + (size_t)row * En;
    reinterpret_cast<float4*>(op)[lane * 2]     = o0;
    reinterpret_cast<float4*>(op)[lane * 2 + 1] = o1;
}

extern "C" void kernel_launch(void* const* d_in, const int* in_sizes, int n_in,
                              void* d_out, int out_size, void* d_ws, size_t ws_size,
                              hipStream_t stream) {
    const float* x     = (const float*)d_in[0];
    const float* W     = (const float*)d_in[1];
    const float* bias  = (const float*)d_in[2];
    const float* C     = (const float*)d_in[3];
    const float* gamma = (const float*)d_in[4];
    const float* beta  = (const float*)d_in[5];
    float* out = (float*)d_out;

    unsigned short* hb  = (unsigned short*)d_ws;             // head-major h (f16)
    unsigned short* Sg  = hb + (size_t)Hn * NT * Dn;         // head-major S (f16), then y (f16)
    unsigned short* Cl  = Sg + (size_t)Hn * NT * Dn;         // C image (f16)
    unsigned short* Wt  = Cl + (size_t)Hn * Dn * Dn * Dn;    // W^T (f16)
    float* locals = (float*)(Wt + (size_t)En * En);

    prep_k<<<512, 256, 0, stream>>>(C, Cl, W, Wt);
    gemm_mfma_k<<<dim3(NT / 128, En / 128), 256, 0, stream>>>(x, Wt, bias, hb, locals);
    scan_emit3_k<<<dim3(NC, Bn), 512, 0, stream>>>(hb, locals, Sg);
    bilinear16_k<<<dim3(NT / 128, Hn), 256, 0, stream>>>(hb, Sg, Sg /*y in-place over S*/, Cl);
    ln_k<<<NT / 4, 256, 0, stream>>>(Sg, gamma, beta, out);
}

// Round 22
// 76.457 us; speedup vs baseline: 1.0407x; 1.0407x over previous
//
#include <hip/hip_runtime.h>
#include <hip/hip_bf16.h>

// Problem constants
#define Bn 8
#define Tn 2048
#define En 512
#define Hn 16
#define Dn 32
#define NC 32          // scan chunks
#define CL 64          // chunk length (Tn/NC)
#define NT (Bn*Tn)     // 16384 tokens
#define INV_DECAY (1.0f/1.2f)

typedef __attribute__((ext_vector_type(8))) _Float16 f16x8; // 8 fp16 (4 VGPRs)
typedef __attribute__((ext_vector_type(2))) _Float16 f16x2;
typedef __attribute__((ext_vector_type(4))) float  f32x4;
typedef __attribute__((ext_vector_type(8))) unsigned short u16x8;

__device__ __forceinline__ unsigned short f2h(float f) {
    union { _Float16 h; unsigned short u; } c; c.h = (_Float16)f; return c.u;
}
__device__ __forceinline__ float h2f(unsigned short u) {
    union { _Float16 h; unsigned short u; } c; c.u = u; return (float)c.h;
}

// (1/1.2)^e, compile-time folded under full unroll
__host__ __device__ constexpr float wpow(int e) {
    float r = 1.f;
    for (int i = 0; i < e; i++) r *= (1.0f / 1.2f);
    return r;
}

// Head-major address: hm[hd][tok][ch], ch in [0,32)
__device__ __forceinline__ size_t hm(int hd, int tok, int ch) {
    return (size_t)hd * ((size_t)NT * Dn) + (size_t)tok * Dn + ch;
}

// ---------------- K0: prep --------------------------------------------------
// blocks 0..255: relayout C f32 -> f16 per-lane-contiguous image.
// blocks 256..511: W[k][n] f32 -> Wt[n][k] f16 (transpose).
__global__ __launch_bounds__(256) void prep_k(const float* __restrict__ C,
                                              unsigned short* __restrict__ Cl,
                                              const float* __restrict__ W,
                                              unsigned short* __restrict__ Wt) {
    __shared__ float tile[32][33];
    if (blockIdx.x < 256) {
        const int g = blockIdx.x * 256 + threadIdx.x;   // 65536 chunks
        const int hd = g >> 12, rem = g & 4095;
        const int i = rem >> 7, half = (rem >> 6) & 1, lane = rem & 63;
        const int tloc = lane & 15, kgrp = lane >> 4;
        const int k = half * 16 + tloc;
        const float* src = C + (size_t)hd * 32768 + (size_t)k * 1024 + i * 32 + kgrp * 8;
        float4 a = reinterpret_cast<const float4*>(src)[0];
        float4 b = reinterpret_cast<const float4*>(src)[1];
        u16x8 st;
        st[0]=f2h(a.x); st[1]=f2h(a.y); st[2]=f2h(a.z); st[3]=f2h(a.w);
        st[4]=f2h(b.x); st[5]=f2h(b.y); st[6]=f2h(b.z); st[7]=f2h(b.w);
        *reinterpret_cast<u16x8*>(Cl + (size_t)g * 8) = st;
    } else {
        const int bid = blockIdx.x - 256;
        const int kb = (bid & 15) * 32, nb = (bid >> 4) * 32;
        const int tx = threadIdx.x & 31, ty = threadIdx.x >> 5;   // ty 0..7
        #pragma unroll
        for (int j = 0; j < 4; j++)
            tile[ty + 8 * j][tx] = W[(size_t)(kb + ty + 8 * j) * En + nb + tx];
        __syncthreads();
        #pragma unroll
        for (int j = 0; j < 4; j++)
            Wt[(size_t)(nb + ty + 8 * j) * En + kb + tx] = f2h(tile[tx][ty + 8 * j]);
    }
}

// ---------------- K1: h = x @ W + b  (f16 MFMA GEMM, 128x128 tile) ----------
__global__ __launch_bounds__(256) void gemm_mfma_k(const float* __restrict__ x,
                                                   const unsigned short* __restrict__ Wt,
                                                   const float* __restrict__ bias,
                                                   unsigned short* __restrict__ h,
                                                   float* __restrict__ locals) {
    __shared__ unsigned short As[128][40];
    __shared__ unsigned short Bs[128][40];
    const int m0 = blockIdx.x * 128, n0 = blockIdx.y * 128;
    const int tid = threadIdx.x;
    const int wid = tid >> 6, lane = tid & 63;
    const int tloc = lane & 15, kgrp = lane >> 4;
    const int wr = wid >> 1, wc = wid & 1;

    const int sr = tid >> 1, sh = (tid & 1) * 16;

    f32x4 acc[4][4] = {};

    for (int k0 = 0; k0 < En; k0 += 32) {
        const float* xp = &x[(size_t)(m0 + sr) * En + k0 + sh];
        float4 a0 = reinterpret_cast<const float4*>(xp)[0];
        float4 a1 = reinterpret_cast<const float4*>(xp)[1];
        float4 a2 = reinterpret_cast<const float4*>(xp)[2];
        float4 a3 = reinterpret_cast<const float4*>(xp)[3];
        const unsigned short* wp = &Wt[(size_t)(n0 + sr) * En + k0 + sh];
        u16x8 bv0 = reinterpret_cast<const u16x8*>(wp)[0];
        u16x8 bv1 = reinterpret_cast<const u16x8*>(wp)[1];
        __syncthreads();
        u16x8 w0, w1;
        w0[0]=f2h(a0.x); w0[1]=f2h(a0.y); w0[2]=f2h(a0.z); w0[3]=f2h(a0.w);
        w0[4]=f2h(a1.x); w0[5]=f2h(a1.y); w0[6]=f2h(a1.z); w0[7]=f2h(a1.w);
        w1[0]=f2h(a2.x); w1[1]=f2h(a2.y); w1[2]=f2h(a2.z); w1[3]=f2h(a2.w);
        w1[4]=f2h(a3.x); w1[5]=f2h(a3.y); w1[6]=f2h(a3.z); w1[7]=f2h(a3.w);
        *reinterpret_cast<u16x8*>(&As[sr][sh])     = w0;
        *reinterpret_cast<u16x8*>(&As[sr][sh + 8]) = w1;
        *reinterpret_cast<u16x8*>(&Bs[sr][sh])     = bv0;
        *reinterpret_cast<u16x8*>(&Bs[sr][sh + 8]) = bv1;
        __syncthreads();

        f16x8 afr[4], bfr[4];
        #pragma unroll
        for (int m = 0; m < 4; m++)
            afr[m] = *reinterpret_cast<const f16x8*>(&As[wr * 64 + m * 16 + tloc][kgrp * 8]);
        #pragma unroll
        for (int n = 0; n < 4; n++)
            bfr[n] = *reinterpret_cast<const f16x8*>(&Bs[wc * 64 + n * 16 + tloc][kgrp * 8]);
        #pragma unroll
        for (int m = 0; m < 4; m++)
            #pragma unroll
            for (int n = 0; n < 4; n++)
                acc[m][n] = __builtin_amdgcn_mfma_f32_16x16x32_f16(afr[m], bfr[n], acc[m][n], 0, 0, 0);
    }

    const float kmul = (kgrp & 1 ? 2.0736f : 1.f) * (kgrp & 2 ? 4.29981696f : 1.f);
    const int cg = blockIdx.x * 2 + wr;   // global 64-token chunk

    #pragma unroll
    for (int nt = 0; nt < 4; nt++) {
        const int col = n0 + wc * 64 + nt * 16 + tloc;
        const float bcol = bias[col];
        const int hd = col >> 5, ch = col & 31;
        float part = 0.f;
        #pragma unroll
        for (int m = 0; m < 4; m++)
            #pragma unroll
            for (int r = 0; r < 4; r++) {
                const int row = m0 + wr * 64 + m * 16 + kgrp * 4 + r;
                const unsigned short hb16 = f2h(acc[m][nt][r] + bcol);
                h[hm(hd, row, ch)] = hb16;
                part += h2f(hb16) * (wpow(64 - m * 16 - r) * kmul);
            }
        part += __shfl_xor(part, 16);
        part += __shfl_xor(part, 32);
        if (kgrp == 0) locals[(size_t)cg * En + col] = part;
    }
}

// ---------------- K2: fused prefix + emit S (f16, head-major) ---------------
__global__ __launch_bounds__(512) void scan_emit3_k(const unsigned short* __restrict__ h,
                                                    const float* __restrict__ locals,
                                                    unsigned short* __restrict__ Sg) {
    const int c = blockIdx.x, b = blockIdx.y;
    const int e = threadIdx.x;
    const int hd = e >> 5, ch = e & 31;
    constexpr float INVRL = wpow(64);   // d^64

    float A = 0.f, w = 1.f;
    for (int cp = c - 1; cp >= 0; --cp) {
        A += w * locals[(size_t)(b * NC + cp) * En + e];
        w *= INVRL;
    }

    const size_t base = hm(hd, b * Tn + c * CL, ch);
    for (int t = 0; t < CL; t++) {
        Sg[base + (size_t)t * Dn] = f2h(A);
        A = (A + h2f(h[base + (size_t)t * Dn])) * INV_DECAY;
    }
}

// ---------------- K3: bilinear v15 — full fp16 datapath (r20 champion) ------
__global__ __launch_bounds__(256, 4) void bilinear15_k(const unsigned short* __restrict__ hg,
                                                       const unsigned short* __restrict__ Sg,
                                                       unsigned short* __restrict__ yb,
                                                       const unsigned short* __restrict__ Cl) {
    __shared__ float ys[4][64][36];   // 36.9 KB

    const int hd = blockIdx.y;
    const int tid = threadIdx.x;
    const int wid = tid >> 6, lane = tid & 63;
    const int tloc = lane & 15, kgrp = lane >> 4;
    const int j0 = kgrp * 8;
    const int tokens0 = blockIdx.x * 64;

    // ---- A-frags: C2 slice (f16), coalesced 16B/lane ----
    f16x8 afr[8][2];
    {
        const unsigned short* cb = Cl + (size_t)hd * 32768;
        #pragma unroll
        for (int s = 0; s < 8; s++) {
            const int i = wid * 8 + s;
            #pragma unroll
            for (int mt = 0; mt < 2; mt++)
                afr[s][mt] = *reinterpret_cast<const f16x8*>(
                    cb + ((size_t)((i * 2 + mt) * 64 + lane) * 8));
        }
    }

    // ---- h (f16 direct) + S (f16 pairs) fragments per n-tile ----
    f16x8 hreg[4];
    f16x2 sf2[4][4];
    #pragma unroll
    for (int nt = 0; nt < 4; nt++) {
        const int trow = tokens0 + nt * 16 + tloc;
        hreg[nt] = *reinterpret_cast<const f16x8*>(hg + hm(hd, trow, wid * 8));
        f16x8 svh = *reinterpret_cast<const f16x8*>(Sg + hm(hd, trow, j0));
        #pragma unroll
        for (int e2 = 0; e2 < 4; e2++) {
            f16x2 p; p.x = svh[e2 * 2]; p.y = svh[e2 * 2 + 1];
            sf2[nt][e2] = p;
        }
    }

    // ---- main loop: pk_mul product gen + 8 indep f16 MFMA chains ----
    f32x4 acc[2][4] = {};
    #pragma unroll
    for (int s = 0; s < 8; s++) {
        #pragma unroll
        for (int nt = 0; nt < 4; nt++) {
            f16x2 hb; hb.x = hreg[nt][s]; hb.y = hreg[nt][s];
            union { f16x8 v; f16x2 p[4]; } bf;
            bf.p[0] = sf2[nt][0] * hb;
            bf.p[1] = sf2[nt][1] * hb;
            bf.p[2] = sf2[nt][2] * hb;
            bf.p[3] = sf2[nt][3] * hb;
            acc[0][nt] = __builtin_amdgcn_mfma_f32_16x16x32_f16(afr[s][0], bf.v, acc[0][nt], 0, 0, 0);
            acc[1][nt] = __builtin_amdgcn_mfma_f32_16x16x32_f16(afr[s][1], bf.v, acc[1][nt], 0, 0, 0);
        }
    }

    // ---- partials to LDS ----
    #pragma unroll
    for (int mt = 0; mt < 2; mt++)
        #pragma unroll
        for (int nt = 0; nt < 4; nt++)
            *reinterpret_cast<f32x4*>(&ys[wid][nt * 16 + tloc][mt * 16 + kgrp * 4]) = acc[mt][nt];
    __syncthreads();

    // ---- reduce 4 partials + residual (f16), coalesced f16 store ----
    {
        const int token = tid >> 2, q = tid & 3;
        f32x4 y0 = {0.f,0.f,0.f,0.f}, y1 = {0.f,0.f,0.f,0.f};
        #pragma unroll
        for (int w = 0; w < 4; w++) {
            const f32x4* src = reinterpret_cast<const f32x4*>(&ys[w][token][q * 8]);
            y0 += src[0];
            y1 += src[1];
        }
        u16x8 hres = *reinterpret_cast<const u16x8*>(hg + hm(hd, tokens0 + token, q * 8));
        u16x8 st;
        #pragma unroll
        for (int e = 0; e < 4; e++) {
            st[e]     = f2h(y0[e] + h2f(hres[e]));
            st[4 + e] = f2h(y1[e] + h2f(hres[4 + e]));
        }
        *reinterpret_cast<u16x8*>(yb + hm(hd, tokens0 + token, q * 8)) = st;
    }
}

// ---------------- K4: LayerNorm over E=512 (head-major f16 in, f32 out) -----
__global__ __launch_bounds__(256) void ln_k(const unsigned short* __restrict__ y,
                                            const float* __restrict__ gamma,
                                            const float* __restrict__ beta,
                                            float* __restrict__ out) {
    const int row = blockIdx.x * 4 + (threadIdx.x >> 6);
    const int lane = threadIdx.x & 63;
    u16x8 v = *reinterpret_cast<const u16x8*>(y + hm(lane >> 2, row, (lane & 3) * 8));
    float f[8];
    float s = 0.f, s2 = 0.f;
    #pragma unroll
    for (int e = 0; e < 8; e++) {
        f[e] = h2f(v[e]);
        s += f[e]; s2 += f[e] * f[e];
    }
    #pragma unroll
    for (int off = 1; off < 64; off <<= 1) {
        s  += __shfl_xor(s, off);
        s2 += __shfl_xor(s2, off);
    }
    const float mu = s * (1.f / En);
    const float var = s2 * (1.f / En) - mu * mu;
    const float rs = rsqrtf(var + 1e-3f);
    const int cbase = lane * 8;
    float4 g0 = reinterpret_cast<const float4*>(&gamma[cbase])[0];
    float4 g1 = reinterpret_cast<const float4*>(&gamma[cbase])[1];
    float4 b0 = reinterpret_cast<const float4*>(&beta[cbase])[0];
    float4 b1 = reinterpret_cast<const float4*>(&beta[cbase])[1];
    float4 o0, o1;
    o0.x = (f[0] - mu) * rs * g0.x + b0.x; o0.y = (f[1] - mu) * rs * g0.y + b0.y;
    o0.z = (f[2] - mu) * rs * g0.z + b0.z; o0.w = (f[3] - mu) * rs * g0.w + b0.w;
    o1.x = (f[4] - mu) * rs * g1.x + b1.x; o1.y = (f[5] - mu) * rs * g1.y + b1.y;
    o1.z = (f[6] - mu) * rs * g1.z + b1.z; o1.w = (f[7] - mu) * rs * g1.w + b1.w;
    float* op = out + (size_t)row * En;
    reinterpret_cast<float4*>(op)[lane * 2]     = o0;
    reinterpret_cast<float4*>(op)[lane * 2 + 1] = o1;
}

extern "C" void kernel_launch(void* const* d_in, const int* in_sizes, int n_in,
                              void* d_out, int out_size, void* d_ws, size_t ws_size,
                              hipStream_t stream) {
    const float* x     = (const float*)d_in[0];
    const float* W     = (const float*)d_in[1];
    const float* bias  = (const float*)d_in[2];
    const float* C     = (const float*)d_in[3];
    const float* gamma = (const float*)d_in[4];
    const float* beta  = (const float*)d_in[5];
    float* out = (float*)d_out;

    unsigned short* hb  = (unsigned short*)d_ws;             // head-major h (f16)
    unsigned short* Sg  = hb + (size_t)Hn * NT * Dn;         // head-major S (f16), then y (f16)
    unsigned short* Cl  = Sg + (size_t)Hn * NT * Dn;         // C image (f16)
    unsigned short* Wt  = Cl + (size_t)Hn * Dn * Dn * Dn;    // W^T (f16)
    float* locals = (float*)(Wt + (size_t)En * En);

    prep_k<<<512, 256, 0, stream>>>(C, Cl, W, Wt);
    gemm_mfma_k<<<dim3(NT / 128, En / 128), 256, 0, stream>>>(x, Wt, bias, hb, locals);
    scan_emit3_k<<<dim3(NC, Bn), 512, 0, stream>>>(hb, locals, Sg);
    bilinear15_k<<<dim3(NT / CL, Hn), 256, 0, stream>>>(hb, Sg, Sg /*y in-place over S*/, Cl);
    ln_k<<<NT / 4, 256, 0, stream>>>(Sg, gamma, beta, out);
}